// Round 1
// baseline (180.111 us; speedup 1.0000x reference)
//
#include <hip/hip_runtime.h>

#define NN 8192
#define FIN 512
#define FO 64

typedef short bf16x8 __attribute__((ext_vector_type(8)));
typedef float f32x4 __attribute__((ext_vector_type(4)));

union AFrag { bf16x8 v; __bf16 b[8]; };
union BFrag { bf16x8 v; uint2 q[2]; };

// ---------------- kernel 0: W[512][64] f32 -> WT[64][512] bf16 ----------------
__global__ void wt_kernel(const float* __restrict__ W, __bf16* __restrict__ WT) {
    const int f = blockIdx.x;   // 0..63
    const int k = threadIdx.x;  // 0..511
    WT[f * FIN + k] = (__bf16)W[k * FO + f];
}

// ---------------- kernel 1: Wh = x@W (bf16 MFMA), emit WhT bf16 + s + t ------
__global__ __launch_bounds__(128) void wh_kernel(
    const float* __restrict__ x, const __bf16* __restrict__ WT,
    const float* __restrict__ a, __bf16* __restrict__ WhT,
    float* __restrict__ s_out, float* __restrict__ t_out)
{
    __shared__ float whlds[2][16][FO];
    const int w  = threadIdx.x >> 6;
    const int l  = threadIdx.x & 63;
    const int lr = l & 15, lg = l >> 4;
    const int rb = (blockIdx.x * 2 + w) * 16;   // 16 rows per wave

    f32x4 acc[4] = {};
    const float* xr = x + (size_t)(rb + lr) * FIN;
    const __bf16* wbase[4];
    #pragma unroll
    for (int ft = 0; ft < 4; ++ft) wbase[ft] = WT + (ft*16 + lr) * FIN;

    for (int ks = 0; ks < 16; ++ks) {
        const int k0 = ks*32 + lg*4;
        const float4 xa = *(const float4*)(xr + k0);
        const float4 xb = *(const float4*)(xr + k0 + 16);
        AFrag af;
        af.b[0]=(__bf16)xa.x; af.b[1]=(__bf16)xa.y; af.b[2]=(__bf16)xa.z; af.b[3]=(__bf16)xa.w;
        af.b[4]=(__bf16)xb.x; af.b[5]=(__bf16)xb.y; af.b[6]=(__bf16)xb.z; af.b[7]=(__bf16)xb.w;
        #pragma unroll
        for (int ft = 0; ft < 4; ++ft) {
            BFrag bf;
            bf.q[0] = *(const uint2*)(wbase[ft] + k0);
            bf.q[1] = *(const uint2*)(wbase[ft] + k0 + 16);
            acc[ft] = __builtin_amdgcn_mfma_f32_16x16x32_bf16(af.v, bf.v, acc[ft], 0, 0, 0);
        }
    }

    // stash f32 Wh tile to LDS (for transposed bf16 store)
    #pragma unroll
    for (int ft = 0; ft < 4; ++ft)
        #pragma unroll
        for (int q = 0; q < 4; ++q)
            whlds[w][lg*4+q][ft*16+lr] = acc[ft][q];

    // s = Wh@a1, t = Wh@a2 (per-row, reduce across the 16-lane f groups)
    float sp[4] = {0,0,0,0}, tp[4] = {0,0,0,0};
    #pragma unroll
    for (int ft = 0; ft < 4; ++ft) {
        const float a1 = a[ft*16 + lr];
        const float a2 = a[FO + ft*16 + lr];
        #pragma unroll
        for (int q = 0; q < 4; ++q) { sp[q] += acc[ft][q]*a1; tp[q] += acc[ft][q]*a2; }
    }
    #pragma unroll
    for (int d = 1; d < 16; d <<= 1) {
        #pragma unroll
        for (int q = 0; q < 4; ++q) { sp[q] += __shfl_xor(sp[q], d); tp[q] += __shfl_xor(tp[q], d); }
    }
    if (lr == 0) {
        *(float4*)(s_out + rb + lg*4) = make_float4(sp[0], sp[1], sp[2], sp[3]);
        *(float4*)(t_out + rb + lg*4) = make_float4(tp[0], tp[1], tp[2], tp[3]);
    }

    // transposed store: lane l owns feature f=l, packs 16 bf16 (rows rb..rb+15)
    unsigned out32[8];
    #pragma unroll
    for (int j = 0; j < 8; ++j) {
        union { __bf16 b; unsigned short u; } c0, c1;
        c0.b = (__bf16)whlds[w][2*j][l];
        c1.b = (__bf16)whlds[w][2*j+1][l];
        out32[j] = (unsigned)c0.u | ((unsigned)c1.u << 16);
    }
    uint4* dst = (uint4*)(WhT + (size_t)l * NN + rb);
    dst[0] = make_uint4(out32[0], out32[1], out32[2], out32[3]);
    dst[1] = make_uint4(out32[4], out32[5], out32[6], out32[7]);
}

// ---------------- kernel 2: fused masked-softmax attention ----------------
// out[i,:] = elu( (sum_j adj_ij * exp(leaky(s_i+t_j)) * Wh[j,:]) / (sum_j adj_ij * exp(...)) )
__global__ __launch_bounds__(512, 4) void gat_kernel(
    const int* __restrict__ adj, const __bf16* __restrict__ WhT,
    const float* __restrict__ s_in, const float* __restrict__ t_in,
    float* __restrict__ out)
{
    __shared__ float red[8][16][FO];
    __shared__ float dnl[8][16];
    const int w  = threadIdx.x >> 6;   // wave id: K-split over 8 j-chunks
    const int l  = threadIdx.x & 63;
    const int lr = l & 15, lg = l >> 4;
    const int rg = blockIdx.x;         // 16-row tile
    const int R  = rg * 16 + lr;
    const float sv = s_in[R];
    const int* adjr = adj + (size_t)R * NN;
    const __bf16* wbase[4];
    #pragma unroll
    for (int ft = 0; ft < 4; ++ft) wbase[ft] = WhT + (size_t)(ft*16 + lr) * NN;

    f32x4 acc[4] = {};
    float dn = 0.f;

    int j0 = w * 1024 + lg * 4;
    int4 nA0 = *(const int4*)(adjr + j0);
    int4 nA1 = *(const int4*)(adjr + j0 + 16);

    #pragma unroll 2
    for (int st = 0; st < 32; ++st) {
        const int jc = j0;
        const int4 A0 = nA0, A1 = nA1;
        j0 += (st < 31) ? 32 : 0;          // 1-deep prefetch of the HBM adj stream
        nA0 = *(const int4*)(adjr + j0);
        nA1 = *(const int4*)(adjr + j0 + 16);

        const float4 T0 = *(const float4*)(t_in + jc);
        const float4 T1 = *(const float4*)(t_in + jc + 16);

        const int   av[8] = {A0.x, A0.y, A0.z, A0.w, A1.x, A1.y, A1.z, A1.w};
        const float tv[8] = {T0.x, T0.y, T0.z, T0.w, T1.x, T1.y, T1.z, T1.w};
        float p[8];
        #pragma unroll
        for (int i = 0; i < 8; ++i) {
            float e = sv + tv[i];
            e = fmaxf(e, 0.2f * e);        // leaky_relu (no max-shift needed: |e|<~12)
            p[i] = av[i] ? __expf(e) : 0.f;
            dn += p[i];
        }
        AFrag af;
        #pragma unroll
        for (int i = 0; i < 8; ++i) af.b[i] = (__bf16)p[i];
        #pragma unroll
        for (int ft = 0; ft < 4; ++ft) {
            BFrag bf;
            bf.q[0] = *(const uint2*)(wbase[ft] + jc);
            bf.q[1] = *(const uint2*)(wbase[ft] + jc + 16);
            acc[ft] = __builtin_amdgcn_mfma_f32_16x16x32_bf16(af.v, bf.v, acc[ft], 0, 0, 0);
        }
    }

    // row-denominator: sum the 4 lane-groups (j sub-slices) of this wave
    dn += __shfl_xor(dn, 16);
    dn += __shfl_xor(dn, 32);

    #pragma unroll
    for (int ft = 0; ft < 4; ++ft)
        #pragma unroll
        for (int q = 0; q < 4; ++q)
            red[w][lg*4+q][ft*16+lr] = acc[ft][q];
    if (l < 16) dnl[w][l] = dn;
    __syncthreads();

    // cross-wave reduce + normalize + ELU
    for (int o = threadIdx.x; o < 16*FO; o += 512) {
        const int row = o >> 6, f = o & 63;
        float v = 0.f, den = 0.f;
        #pragma unroll
        for (int ww = 0; ww < 8; ++ww) { v += red[ww][row][f]; den += dnl[ww][row]; }
        const float h = v / den;
        out[(size_t)(rg*16 + row) * FO + f] = (h > 0.f) ? h : (__expf(h) - 1.f);
    }
}

extern "C" void kernel_launch(void* const* d_in, const int* in_sizes, int n_in,
                              void* d_out, int out_size, void* d_ws, size_t ws_size,
                              hipStream_t stream) {
    const float* x   = (const float*)d_in[0];
    const int*   adj = (const int*)d_in[1];
    const float* W   = (const float*)d_in[2];
    const float* a   = (const float*)d_in[3];
    float* out = (float*)d_out;

    char* ws = (char*)d_ws;
    __bf16* WhT = (__bf16*)ws;                               // 64*8192*2 = 1 MiB
    __bf16* WT  = (__bf16*)(ws + (1u << 20));                // 64*512*2  = 64 KiB
    float*  s   = (float*)(ws + (1u << 20) + (1u << 16));    // 32 KiB
    float*  t   = (float*)(ws + (1u << 20) + (1u << 16) + 32768);  // 32 KiB

    wt_kernel<<<64, 512, 0, stream>>>(W, WT);
    wh_kernel<<<256, 128, 0, stream>>>(x, WT, a, WhT, s, t);
    gat_kernel<<<512, 512, 0, stream>>>(adj, WhT, s, t, out);
}

// Round 2
// 95.459 us; speedup vs baseline: 1.8868x; 1.8868x over previous
//
#include <hip/hip_runtime.h>

#define NN 8192
#define FIN 512
#define FO 64

typedef short bf16x8 __attribute__((ext_vector_type(8)));
typedef float f32x4 __attribute__((ext_vector_type(4)));

union AFrag { bf16x8 v; __bf16 b[8]; };

// ---------------- kernel 0: W[512][64] f32 -> WT[64][512] bf16 ----------------
__global__ void wt_kernel(const float* __restrict__ W, __bf16* __restrict__ WT) {
    const int f = blockIdx.x;   // 0..63
    const int k = threadIdx.x;  // 0..511
    WT[f * FIN + k] = (__bf16)W[k * FO + f];
}

// ---------------- kernel 1: Wh = x@W (bf16 MFMA), emit swizzled Wh + s + t ---
// Output whs: per 32-col block jb, per ft (0..3), per lane l: uint4 = the 8
// bf16 B-fragment elements for mfma_f32_16x16x32_bf16 —
//   feature = ft*16 + (l&15); cols = jb*32 + (l>>4)*4 + {0..3} and +16+{0..3}.
__global__ __launch_bounds__(128) void wh_kernel(
    const float* __restrict__ x, const __bf16* __restrict__ WT,
    const float* __restrict__ a, uint4* __restrict__ whs,
    float* __restrict__ s_out, float* __restrict__ t_out)
{
    __shared__ float whlds[2][16][FO + 1];
    const int w  = threadIdx.x >> 6;
    const int l  = threadIdx.x & 63;
    const int lr = l & 15, lg = l >> 4;
    const int rb = (blockIdx.x * 2 + w) * 16;   // 16 rows per wave

    f32x4 acc[4] = {};
    const float* xr = x + (size_t)(rb + lr) * FIN;
    const __bf16* wbase[4];
    #pragma unroll
    for (int ft = 0; ft < 4; ++ft) wbase[ft] = WT + (ft*16 + lr) * FIN;

    for (int ks = 0; ks < 16; ++ks) {
        const int k0 = ks*32 + lg*4;
        const float4 xa = *(const float4*)(xr + k0);
        const float4 xb = *(const float4*)(xr + k0 + 16);
        AFrag af;
        af.b[0]=(__bf16)xa.x; af.b[1]=(__bf16)xa.y; af.b[2]=(__bf16)xa.z; af.b[3]=(__bf16)xa.w;
        af.b[4]=(__bf16)xb.x; af.b[5]=(__bf16)xb.y; af.b[6]=(__bf16)xb.z; af.b[7]=(__bf16)xb.w;
        #pragma unroll
        for (int ft = 0; ft < 4; ++ft) {
            union { bf16x8 v; uint2 q[2]; } bf;
            bf.q[0] = *(const uint2*)(wbase[ft] + k0);
            bf.q[1] = *(const uint2*)(wbase[ft] + k0 + 16);
            acc[ft] = __builtin_amdgcn_mfma_f32_16x16x32_bf16(af.v, bf.v, acc[ft], 0, 0, 0);
        }
    }

    // stash f32 Wh tile to LDS
    #pragma unroll
    for (int ft = 0; ft < 4; ++ft)
        #pragma unroll
        for (int q = 0; q < 4; ++q)
            whlds[w][lg*4+q][ft*16+lr] = acc[ft][q];

    // s = Wh@a1, t = Wh@a2 (per-row, reduce across the 16-lane f groups)
    float sp[4] = {0,0,0,0}, tp[4] = {0,0,0,0};
    #pragma unroll
    for (int ft = 0; ft < 4; ++ft) {
        const float a1 = a[ft*16 + lr];
        const float a2 = a[FO + ft*16 + lr];
        #pragma unroll
        for (int q = 0; q < 4; ++q) { sp[q] += acc[ft][q]*a1; tp[q] += acc[ft][q]*a2; }
    }
    #pragma unroll
    for (int d = 1; d < 16; d <<= 1) {
        #pragma unroll
        for (int q = 0; q < 4; ++q) { sp[q] += __shfl_xor(sp[q], d); tp[q] += __shfl_xor(tp[q], d); }
    }
    if (lr == 0) {
        *(float4*)(s_out + rb + lg*4) = make_float4(sp[0], sp[1], sp[2], sp[3]);
        *(float4*)(t_out + rb + lg*4) = make_float4(tp[0], tp[1], tp[2], tp[3]);
    }

    __syncthreads();

    // swizzled fragment store: this block's 32 rows = column-block jb
    const int jb = blockIdx.x;
    #pragma unroll
    for (int q = 0; q < 2; ++q) {
        const int ft = w*2 + q;          // 0..3
        const int f  = ft*16 + lr;
        unsigned u[4];
        #pragma unroll
        for (int h = 0; h < 4; ++h) {
            const int c0 = ((h & 2) ? 16 : 0) + lg*4 + (h & 1)*2;  // local col
            union { __bf16 b; unsigned short us; } lo, hi;
            lo.b = (__bf16)whlds[c0 >> 4][c0 & 15][f];
            hi.b = (__bf16)whlds[(c0+1) >> 4][(c0+1) & 15][f];
            u[h] = (unsigned)lo.us | ((unsigned)hi.us << 16);
        }
        whs[(jb*4 + ft)*64 + l] = make_uint4(u[0], u[1], u[2], u[3]);
    }
}

// ---------------- kernel 2: fused masked-softmax attention ----------------
// out[i,:] = elu( (sum_j adj_ij * exp(leaky(s_i+t_j)) * Wh[j,:]) / denom )
__global__ __launch_bounds__(1024, 8) void gat_kernel(
    const int* __restrict__ adj, const uint4* __restrict__ whs,
    const float* __restrict__ s_in, const float* __restrict__ t_in,
    float* __restrict__ out)
{
    __shared__ float red[16][16][FO];
    __shared__ float dnl[16][16];
    const int w  = threadIdx.x >> 6;   // wave id 0..15: K-split over 16 j-chunks
    const int l  = threadIdx.x & 63;
    const int lr = l & 15, lg = l >> 4;
    const int rg = blockIdx.x;         // 16-row tile
    const int R  = rg * 16 + lr;
    const float sv = s_in[R];
    const int* adjr = adj + (size_t)R * NN;
    const bf16x8* wv = (const bf16x8*)whs;

    f32x4 acc[4] = {};
    float dn = 0.f;

    #pragma unroll 2
    for (int st = 0; st < 16; ++st) {
        const int jc = w*512 + st*32 + lg*4;   // this lane's column base
        const int jb = w*16 + st;              // global 32-col block id

        const int4   A0 = *(const int4*)(adjr + jc);
        const int4   A1 = *(const int4*)(adjr + jc + 16);
        const float4 T0 = *(const float4*)(t_in + jc);
        const float4 T1 = *(const float4*)(t_in + jc + 16);

        const int   av[8] = {A0.x, A0.y, A0.z, A0.w, A1.x, A1.y, A1.z, A1.w};
        const float tv[8] = {T0.x, T0.y, T0.z, T0.w, T1.x, T1.y, T1.z, T1.w};
        float p[8];
        #pragma unroll
        for (int i = 0; i < 8; ++i) {
            float e = sv + tv[i];
            e = fmaxf(e, 0.2f * e);            // leaky_relu (|e| small: no max-shift)
            p[i] = av[i] ? __expf(e) : 0.f;
            dn += p[i];
        }
        AFrag af;
        #pragma unroll
        for (int i = 0; i < 8; ++i) af.b[i] = (__bf16)p[i];
        #pragma unroll
        for (int ft = 0; ft < 4; ++ft) {
            const bf16x8 bv = wv[(jb*4 + ft)*64 + l];   // fully coalesced 1KB/wave
            acc[ft] = __builtin_amdgcn_mfma_f32_16x16x32_bf16(af.v, bv, acc[ft], 0, 0, 0);
        }
    }

    // row-denominator: sum the 4 lane-groups (j sub-slices) of this wave
    dn += __shfl_xor(dn, 16);
    dn += __shfl_xor(dn, 32);

    #pragma unroll
    for (int ft = 0; ft < 4; ++ft)
        #pragma unroll
        for (int q = 0; q < 4; ++q)
            red[w][lg*4+q][ft*16+lr] = acc[ft][q];
    if (l < 16) dnl[w][l] = dn;
    __syncthreads();

    // cross-wave reduce + normalize + ELU: 1024 threads, one output each
    {
        const int row = threadIdx.x >> 6, f = threadIdx.x & 63;
        float v = 0.f, den = 0.f;
        #pragma unroll
        for (int ww = 0; ww < 16; ++ww) { v += red[ww][row][f]; den += dnl[ww][row]; }
        const float h = v / den;
        out[(size_t)(rg*16 + row) * FO + f] = (h > 0.f) ? h : (__expf(h) - 1.f);
    }
}

extern "C" void kernel_launch(void* const* d_in, const int* in_sizes, int n_in,
                              void* d_out, int out_size, void* d_ws, size_t ws_size,
                              hipStream_t stream) {
    const float* x   = (const float*)d_in[0];
    const int*   adj = (const int*)d_in[1];
    const float* W   = (const float*)d_in[2];
    const float* a   = (const float*)d_in[3];
    float* out = (float*)d_out;

    char* ws = (char*)d_ws;
    uint4*  whs = (uint4*)ws;                                // 1 MiB swizzled Wh
    __bf16* WT  = (__bf16*)(ws + (1u << 20));                // 64 KiB
    float*  s   = (float*)(ws + (1u << 20) + (1u << 16));    // 32 KiB
    float*  t   = (float*)(ws + (1u << 20) + (1u << 16) + 32768);  // 32 KiB

    wt_kernel<<<64, 512, 0, stream>>>(W, WT);
    wh_kernel<<<256, 128, 0, stream>>>(x, WT, a, whs, s, t);
    gat_kernel<<<512, 1024, 0, stream>>>(adj, whs, s, t, out);
}